// Round 2
// baseline (1743.041 us; speedup 1.0000x reference)
//
#include <hip/hip_runtime.h>

// act: [256,768,17,17] f32 ; pool(5x5 s3) -> [256,768,5,5]
// conv0: 1x1 768->128 ; conv1: 5x5 128->768 -> 1x1 ; fc: 768->1000
// All quantization-deciding math in f64 to track the np(f64) reference.
#define NB 256
#define NC 768
#define HW 289
#define NP 25
#define OC0 128
#define K1 3200
#define NO 1000

// ws layout in doubles (base also holds 3 uints for absmax)
#define OFF_A0   16
#define SZ_A0    (NB*OC0*NP)       // 819,200
#define OFF_A1   (OFF_A0 + SZ_A0)
#define SZ_A1    (NB*NC)           // 196,608
#define OFF_W0T  (OFF_A1 + SZ_A1)
#define SZ_W0T   (NC*OC0)          // 98,304
#define OFF_FCT  (OFF_W0T + SZ_W0T)
#define SZ_FCT   (NC*NO)           // 768,000
#define OFF_POOL (OFF_FCT + SZ_FCT) // pool f64; later aliased by w1q (w1q smaller)
#define SZ_POOL  (NB*NC*NP)        // 4,915,200  (~54.4 MB total ws in doubles)

__global__ void k_init(unsigned* mx) {
    if (threadIdx.x < 3) mx[threadIdx.x] = 0u;
}

// grid-stride absmax -> atomicMax on uint bits (exact; max is order-independent)
__global__ void k_absmax(const float* __restrict__ w, int n, unsigned* __restrict__ out) {
    float m = 0.f;
    for (int i = blockIdx.x * blockDim.x + threadIdx.x; i < n; i += gridDim.x * blockDim.x)
        m = fmaxf(m, fabsf(w[i]));
    #pragma unroll
    for (int off = 32; off; off >>= 1) m = fmaxf(m, __shfl_down(m, off));
    __shared__ float sm[4];
    if ((threadIdx.x & 63) == 0) sm[threadIdx.x >> 6] = m;
    __syncthreads();
    if (threadIdx.x == 0) {
        float mm = fmaxf(fmaxf(sm[0], sm[1]), fmaxf(sm[2], sm[3]));
        atomicMax(out, __float_as_uint(mm));
    }
}

__device__ __forceinline__ double quantw(double w, double scale) {
    double r = rint(w / scale);           // np.round = half-to-even = rint
    r = fmin(fmax(r, -127.0), 127.0);
    return r * scale;
}

__device__ __forceinline__ double actq(double y, double a) {
    y = fmax(y, 0.0);
    y = fmin(y, a);
    double s = a / 255.0;
    return rint(y / s) * s;
}

// conv0 weights [oc=128][ic=768] -> transposed quantized f64 [ic=768][oc=128]
__global__ void k_qw0t(const float* __restrict__ w, const float* __restrict__ mx,
                       double* __restrict__ out) {
    int i = blockIdx.x * 256 + threadIdx.x;   // 98304
    double scale = (double)mx[0] / 127.0;
    int ic = i / 128, oc = i % 128;
    out[i] = quantw((double)w[oc * 768 + ic], scale);
}

// conv1 weights quant in-layout [oc=768][k=3200] f64
__global__ void k_qw1(const float* __restrict__ w, const float* __restrict__ mx,
                      double* __restrict__ out) {
    int i = blockIdx.x * 256 + threadIdx.x;   // 2,457,600
    double scale = (double)mx[1] / 127.0;
    out[i] = quantw((double)w[i], scale);
}

// fc weights [o=1000][c=768] -> transposed quantized f64 [c=768][o=1000]
__global__ void k_qfct(const float* __restrict__ w, const float* __restrict__ mx,
                       double* __restrict__ out) {
    int i = blockIdx.x * 256 + threadIdx.x;   // 768,000
    double scale = (double)mx[2] / 127.0;
    int c = i / 1000, o = i % 1000;
    out[i] = quantw((double)w[o * 768 + c], scale);
}

// avg_pool k=5 s=3: 8 planes per block, coalesced f32 loads into LDS, f64 sums
__global__ __launch_bounds__(256) void k_pool(const float* __restrict__ x,
                                              double* __restrict__ pool) {
    __shared__ float tile[8 * HW];            // 9248 B
    size_t g = blockIdx.x;                    // 24576 groups of 8 planes
    const float* src = x + g * (8 * HW);
    for (int i = threadIdx.x; i < 8 * HW; i += 256) tile[i] = src[i];
    __syncthreads();
    int t = threadIdx.x;                      // 200 active: plane*25 + p
    if (t < 200) {
        int pl = t / 25, p = t % 25;
        int oh = p / 5, ow = p % 5;
        const float* tp = tile + pl * HW + (oh * 3) * 17 + ow * 3;
        double s = 0.0;
        #pragma unroll
        for (int kh = 0; kh < 5; ++kh)
            #pragma unroll
            for (int kw = 0; kw < 5; ++kw)
                s += (double)tp[kh * 17 + kw];
        pool[g * 200 + t] = s / 25.0;
    }
}

// conv0 1x1 + bn0 + relu + act_quant, f64. out a0[b][oc][p]
__global__ __launch_bounds__(256) void k_conv0(const double* __restrict__ pool,
                                               const double* __restrict__ w0t,
                                               const float* __restrict__ g,
                                               const float* __restrict__ be,
                                               const float* __restrict__ mn,
                                               const float* __restrict__ vr,
                                               const float* __restrict__ alpha,
                                               double* __restrict__ a0) {
    int t = blockIdx.x * 256 + threadIdx.x;   // 819,200
    int b = t / (OC0 * NP);
    int r = t % (OC0 * NP);
    int oc = r / NP, p = r % NP;
    const double* xp = pool + (size_t)b * (NC * NP) + p;
    const double* wp = w0t + oc;
    double acc = 0.0;
    #pragma unroll 4
    for (int ic = 0; ic < NC; ++ic)
        acc += xp[ic * NP] * wp[ic * OC0];
    double inv = (double)g[oc] / sqrt((double)vr[oc] + 1e-3);
    double y = acc * inv + ((double)be[oc] - (double)mn[oc] * inv);
    a0[t] = actq(y, (double)alpha[0]);
}

// conv1 as f64 GEMM: a1[256x768] = actq(bn(A[256x3200] * W[768x3200]^T))
__global__ __launch_bounds__(256) void k_conv1(const double* __restrict__ a0,
                                               const double* __restrict__ w1q,
                                               const float* __restrict__ g,
                                               const float* __restrict__ be,
                                               const float* __restrict__ mn,
                                               const float* __restrict__ vr,
                                               const float* __restrict__ alpha,
                                               double* __restrict__ a1) {
    __shared__ double As[64][17];
    __shared__ double Bs[64][17];
    int b0 = blockIdx.x * 64;      // 4 tiles
    int oc0 = blockIdx.y * 64;     // 12 tiles
    int tid = threadIdx.x;
    int ty = tid / 16, tx = tid % 16;
    int lrow = tid / 4, lk = (tid % 4) * 4;
    double acc[4][4] = {};
    for (int k0 = 0; k0 < K1; k0 += 16) {
        const double* ap = a0 + (size_t)(b0 + lrow) * K1 + k0 + lk;
        const double* bp = w1q + (size_t)(oc0 + lrow) * K1 + k0 + lk;
        #pragma unroll
        for (int q = 0; q < 4; ++q) As[lrow][lk + q] = ap[q];
        #pragma unroll
        for (int q = 0; q < 4; ++q) Bs[lrow][lk + q] = bp[q];
        __syncthreads();
        #pragma unroll
        for (int kk = 0; kk < 16; ++kk) {
            double av[4], bv[4];
            #pragma unroll
            for (int i = 0; i < 4; ++i) av[i] = As[ty * 4 + i][kk];
            #pragma unroll
            for (int j = 0; j < 4; ++j) bv[j] = Bs[tx * 4 + j][kk];
            #pragma unroll
            for (int i = 0; i < 4; ++i)
                #pragma unroll
                for (int j = 0; j < 4; ++j)
                    acc[i][j] += av[i] * bv[j];
        }
        __syncthreads();
    }
    double a = (double)alpha[0];
    #pragma unroll
    for (int j = 0; j < 4; ++j) {
        int oc = oc0 + tx * 4 + j;
        double inv = (double)g[oc] / sqrt((double)vr[oc] + 1e-3);
        double sh = (double)be[oc] - (double)mn[oc] * inv;
        #pragma unroll
        for (int i = 0; i < 4; ++i) {
            int b = b0 + ty * 4 + i;
            double y = acc[i][j] * inv + sh;
            a1[(size_t)b * NC + oc] = actq(y, a);
        }
    }
}

// fc: out[b,o] = sum_c a1[b,c]*fct[c,o] + bias[o] ; 8 batches per block
__global__ __launch_bounds__(256) void k_fc(const double* __restrict__ a1,
                                            const double* __restrict__ fct,
                                            const float* __restrict__ bias,
                                            float* __restrict__ out) {
    __shared__ double xs[8][NC];              // 49 KiB
    int b0 = blockIdx.x * 8;
    for (int i = threadIdx.x; i < 8 * NC; i += 256)
        xs[i / NC][i % NC] = a1[(size_t)(b0 + i / NC) * NC + i % NC];
    __syncthreads();
    for (int o = threadIdx.x; o < NO; o += 256) {
        double acc[8] = {};
        for (int c = 0; c < NC; ++c) {
            double w = fct[(size_t)c * NO + o];
            #pragma unroll
            for (int bb = 0; bb < 8; ++bb)
                acc[bb] += xs[bb][c] * w;
        }
        double bi = (double)bias[o];
        #pragma unroll
        for (int bb = 0; bb < 8; ++bb)
            out[(size_t)(b0 + bb) * NO + o] = (float)(acc[bb] + bi);
    }
}

extern "C" void kernel_launch(void* const* d_in, const int* in_sizes, int n_in,
                              void* d_out, int out_size, void* d_ws, size_t ws_size,
                              hipStream_t stream) {
    const float* act     = (const float*)d_in[0];
    const float* conv0_w = (const float*)d_in[2];
    const float* bn0g = (const float*)d_in[3];
    const float* bn0b = (const float*)d_in[4];
    const float* bn0m = (const float*)d_in[5];
    const float* bn0v = (const float*)d_in[6];
    const float* alpha0 = (const float*)d_in[7];
    const float* conv1_w = (const float*)d_in[8];
    const float* bn1g = (const float*)d_in[9];
    const float* bn1b = (const float*)d_in[10];
    const float* bn1m = (const float*)d_in[11];
    const float* bn1v = (const float*)d_in[12];
    const float* alpha1 = (const float*)d_in[13];
    const float* fc_w = (const float*)d_in[14];
    const float* fc_b = (const float*)d_in[15];

    double* ws = (double*)d_ws;
    unsigned* mxu = (unsigned*)d_ws;
    const float* mxf = (const float*)d_ws;
    double* a0   = ws + OFF_A0;
    double* a1   = ws + OFF_A1;
    double* w0t  = ws + OFF_W0T;
    double* fct  = ws + OFF_FCT;
    double* pool = ws + OFF_POOL;
    double* w1q  = ws + OFF_POOL;   // aliases pool; written only after conv0 done
    float* out = (float*)d_out;

    k_init<<<1, 64, 0, stream>>>(mxu);
    k_absmax<<<256, 256, 0, stream>>>(conv0_w, 98304, mxu + 0);
    k_absmax<<<256, 256, 0, stream>>>(conv1_w, 2457600, mxu + 1);
    k_absmax<<<256, 256, 0, stream>>>(fc_w, 768000, mxu + 2);

    k_qw0t<<<384, 256, 0, stream>>>(conv0_w, mxf, w0t);
    k_qfct<<<3000, 256, 0, stream>>>(fc_w, mxf, fct);

    k_pool<<<24576, 256, 0, stream>>>(act, pool);
    k_conv0<<<3200, 256, 0, stream>>>(pool, w0t, bn0g, bn0b, bn0m, bn0v, alpha0, a0);
    // pool dead from here; w1q aliases its storage
    k_qw1<<<9600, 256, 0, stream>>>(conv1_w, mxf, w1q);
    k_conv1<<<dim3(4, 12), 256, 0, stream>>>(a0, w1q, bn1g, bn1b, bn1m, bn1v, alpha1, a1);
    k_fc<<<32, 256, 0, stream>>>(a1, fct, fc_b, out);
}

// Round 3
// 573.410 us; speedup vs baseline: 3.0398x; 3.0398x over previous
//
#include <hip/hip_runtime.h>

// act: [256,768,17,17] f32 ; pool(5x5 s3) -> [b][p=25][ic=768] f64 (GEMM layout)
// conv0: f64 GEMM [6400x768]x[768x128] + bn + actq -> a0k i8 (k-128), layout [b][oc*25+p]
// conv1: exact int GEMM 256x768x3200 + bn + actq -> a1k i8 (k-128) [256][768]
// fc:    exact int GEMM 256x1000x768 + bias -> f32 out
#define NB 256
#define NC 768
#define HW 289
#define NP 25
#define OC0 128
#define K1 3200
#define NO 1000
#define M0 6400   // NB*NP

// ws layout in BYTES
#define OFF_MX    0
#define OFF_W0T   256                         // f64 [768][128] = 786432 B
#define OFF_POOL  (OFF_W0T + 786432)          // f64 [6400][768] = 39321600 B
#define OFF_A0K   (OFF_POOL + 39321600)       // i8  819200
#define OFF_W1R   (OFF_A0K + 819200)          // i8  2457600
#define OFF_SUMR1 (OFF_W1R + 2457600)         // i32 768
#define OFF_A1K   (OFF_SUMR1 + 4096)          // i8  196608
#define OFF_FCR   (OFF_A1K + 196608)          // i8  768000
#define OFF_SUMFC (OFF_FCR + 768000)          // i32 1000

#if __has_builtin(__builtin_amdgcn_sdot4)
__device__ __forceinline__ int DOT4(unsigned a, unsigned b, int c) {
    return __builtin_amdgcn_sdot4((int)a, (int)b, c, false);
}
#else
__device__ __forceinline__ int DOT4(unsigned a, unsigned b, int c) {
    #pragma unroll
    for (int q = 0; q < 4; ++q)
        c += (int)(char)(a >> (8*q)) * (int)(char)(b >> (8*q));
    return c;
}
#endif

__global__ void k_init(unsigned* mx) {
    if (threadIdx.x < 3) mx[threadIdx.x] = 0u;
}

__global__ void k_absmax(const float* __restrict__ w, int n, unsigned* __restrict__ out) {
    float m = 0.f;
    for (int i = blockIdx.x * blockDim.x + threadIdx.x; i < n; i += gridDim.x * blockDim.x)
        m = fmaxf(m, fabsf(w[i]));
    #pragma unroll
    for (int off = 32; off; off >>= 1) m = fmaxf(m, __shfl_down(m, off));
    __shared__ float sm[4];
    if ((threadIdx.x & 63) == 0) sm[threadIdx.x >> 6] = m;
    __syncthreads();
    if (threadIdx.x == 0)
        atomicMax(out, __float_as_uint(fmaxf(fmaxf(sm[0], sm[1]), fmaxf(sm[2], sm[3]))));
}

// conv0 weights [oc=128][ic=768] -> transposed quantized f64 [ic][oc]
__global__ void k_qw0t(const float* __restrict__ w, const float* __restrict__ mx,
                       double* __restrict__ out) {
    int i = blockIdx.x * 256 + threadIdx.x;           // 98304
    double scale = (double)mx[0] / 127.0;
    int ic = i >> 7, oc = i & 127;
    double r = rint((double)w[oc * 768 + ic] / scale);
    r = fmin(fmax(r, -127.0), 127.0);
    out[i] = r * scale;
}

// per-row weight quant to i8 + row-sum (for the k-128 correction)
__global__ __launch_bounds__(256) void k_qwrow(const float* __restrict__ w, int rowlen,
                                               const float* __restrict__ mx, int mxi,
                                               char* __restrict__ out, int* __restrict__ sumr) {
    int row = blockIdx.x;
    double scale = (double)mx[mxi] / 127.0;
    const float* wr = w + (size_t)row * rowlen;
    char* orow = out + (size_t)row * rowlen;
    int s = 0;
    for (int t = threadIdx.x; t < rowlen; t += 256) {
        double r = rint((double)wr[t] / scale);
        r = fmin(fmax(r, -127.0), 127.0);
        int ri = (int)r;
        s += ri;
        orow[t] = (char)ri;
    }
    #pragma unroll
    for (int off = 32; off; off >>= 1) s += __shfl_down(s, off);
    __shared__ int sm[4];
    if ((threadIdx.x & 63) == 0) sm[threadIdx.x >> 6] = s;
    __syncthreads();
    if (threadIdx.x == 0) sumr[row] = sm[0] + sm[1] + sm[2] + sm[3];
}

// avg_pool 5x5 s3 -> pool_t[(b*25+p)*768 + ic] f64
__global__ __launch_bounds__(256) void k_pool(const float* __restrict__ x,
                                              double* __restrict__ pool_t) {
    __shared__ float tile[8 * HW];
    int g = blockIdx.x;                       // 24576 = 256 b * 96 icg
    int b = g / 96, icg = g % 96;
    const float* src = x + (size_t)g * (8 * HW);
    for (int i = threadIdx.x; i < 8 * HW; i += 256) tile[i] = src[i];
    __syncthreads();
    int t = threadIdx.x;
    if (t < 200) {
        int p = t >> 3, pl = t & 7;           // lanes: 8 consecutive ic per p
        int oh = p / 5, ow = p % 5;
        const float* tp = tile + pl * HW + oh * 51 + ow * 3;
        double s = 0.0;
        #pragma unroll
        for (int kh = 0; kh < 5; ++kh)
            #pragma unroll
            for (int kw = 0; kw < 5; ++kw) s += (double)tp[kh * 17 + kw];
        pool_t[((size_t)b * NP + p) * NC + icg * 8 + pl] = s / 25.0;
    }
}

// conv0: f64 GEMM C[6400x128] = pool_t[6400x768] * w0t[768x128]; bn0+relu+actq -> a0k
__global__ __launch_bounds__(256) void k_conv0(const double* __restrict__ A,
                                               const double* __restrict__ w0t,
                                               const float* __restrict__ g,
                                               const float* __restrict__ be,
                                               const float* __restrict__ mn,
                                               const float* __restrict__ vr,
                                               const float* __restrict__ alpha,
                                               char* __restrict__ a0k) {
    __shared__ double As[32][16];
    __shared__ double Bs[16][128];
    int m0 = blockIdx.x * 32;
    int tid = threadIdx.x;
    int ty = tid >> 5, tx = tid & 31;         // ty 0..7, tx 0..31
    double acc[4][4] = {};
    for (int k0 = 0; k0 < NC; k0 += 16) {
        #pragma unroll
        for (int l = 0; l < 2; ++l) {
            int e = tid + l * 256;
            As[e >> 4][e & 15] = A[(size_t)(m0 + (e >> 4)) * NC + k0 + (e & 15)];
        }
        #pragma unroll
        for (int l = 0; l < 8; ++l) {
            int e = tid + l * 256;
            Bs[e >> 7][e & 127] = w0t[(size_t)(k0 + (e >> 7)) * OC0 + (e & 127)];
        }
        __syncthreads();
        #pragma unroll
        for (int kk = 0; kk < 16; ++kk) {
            double av[4], bv[4];
            #pragma unroll
            for (int i = 0; i < 4; ++i) av[i] = As[ty * 4 + i][kk];
            #pragma unroll
            for (int j = 0; j < 4; ++j) bv[j] = Bs[kk][tx + 32 * j];
            #pragma unroll
            for (int i = 0; i < 4; ++i)
                #pragma unroll
                for (int j = 0; j < 4; ++j)
                    acc[i][j] += av[i] * bv[j];
        }
        __syncthreads();
    }
    double a = (double)alpha[0];
    double s = a / 255.0;
    #pragma unroll
    for (int j = 0; j < 4; ++j) {
        int oc = tx + 32 * j;
        double inv = (double)g[oc] / sqrt((double)vr[oc] + 1e-3);
        double sh = (double)be[oc] - (double)mn[oc] * inv;
        #pragma unroll
        for (int i = 0; i < 4; ++i) {
            int r = m0 + ty * 4 + i;
            int b = r / 25, p = r % 25;
            double y = acc[i][j] * inv + sh;
            y = fmax(y, 0.0); y = fmin(y, a);
            int k = (int)rint(y / s);
            a0k[(size_t)b * K1 + oc * 25 + p] = (char)(k - 128);
        }
    }
}

// conv1: int GEMM C[256x768] = a0k[256x3200] . w1r[768x3200]^T ; bn1+relu+actq -> a1k
__global__ __launch_bounds__(256) void k_conv1(const char* __restrict__ a0k,
                                               const char* __restrict__ w1r,
                                               const int* __restrict__ sumr,
                                               const float* __restrict__ g,
                                               const float* __restrict__ be,
                                               const float* __restrict__ mn,
                                               const float* __restrict__ vr,
                                               const float* __restrict__ alpha0,
                                               const float* __restrict__ alpha1,
                                               const float* __restrict__ mx,
                                               char* __restrict__ a1k) {
    __shared__ unsigned As[32][17];
    __shared__ unsigned Bs[32][17];
    int b0 = blockIdx.x * 32, oc0 = blockIdx.y * 32;
    int tid = threadIdx.x;
    int ty = tid >> 4, tx = tid & 15;
    int acc[2][2] = {};
    for (int k0 = 0; k0 < K1; k0 += 64) {
        int row = tid >> 3, o8 = (tid & 7) * 8;
        uint2 va = *(const uint2*)(a0k + (size_t)(b0 + row) * K1 + k0 + o8);
        As[row][o8 >> 2] = va.x; As[row][(o8 >> 2) + 1] = va.y;
        uint2 vb = *(const uint2*)(w1r + (size_t)(oc0 + row) * K1 + k0 + o8);
        Bs[row][o8 >> 2] = vb.x; Bs[row][(o8 >> 2) + 1] = vb.y;
        __syncthreads();
        #pragma unroll
        for (int kd = 0; kd < 16; ++kd) {
            unsigned av[2], bv[2];
            av[0] = As[ty * 2][kd];     av[1] = As[ty * 2 + 1][kd];
            bv[0] = Bs[tx * 2][kd];     bv[1] = Bs[tx * 2 + 1][kd];
            #pragma unroll
            for (int i = 0; i < 2; ++i)
                #pragma unroll
                for (int j = 0; j < 2; ++j)
                    acc[i][j] = DOT4(av[i], bv[j], acc[i][j]);
        }
        __syncthreads();
    }
    double s_a0 = (double)alpha0[0] / 255.0;
    double s_w1 = (double)mx[1] / 127.0;
    double m = s_a0 * s_w1;
    double a = (double)alpha1[0];
    double s1 = a / 255.0;
    #pragma unroll
    for (int j = 0; j < 2; ++j) {
        int oc = oc0 + tx * 2 + j;
        double inv = (double)g[oc] / sqrt((double)vr[oc] + 1e-3);
        double sh = (double)be[oc] - (double)mn[oc] * inv;
        int corr = 128 * sumr[oc];
        #pragma unroll
        for (int i = 0; i < 2; ++i) {
            int b = b0 + ty * 2 + i;
            double y = (double)(acc[i][j] + corr) * m * inv + sh;
            y = fmax(y, 0.0); y = fmin(y, a);
            int k = (int)rint(y / s1);
            a1k[(size_t)b * NC + oc] = (char)(k - 128);
        }
    }
}

// fc: int GEMM out[256x1000] = a1k[256x768] . fcr[1000x768]^T * s + bias
__global__ __launch_bounds__(256) void k_fc(const char* __restrict__ a1k,
                                            const char* __restrict__ fcr,
                                            const int* __restrict__ sumr,
                                            const float* __restrict__ alpha1,
                                            const float* __restrict__ mx,
                                            const float* __restrict__ bias,
                                            float* __restrict__ out) {
    __shared__ unsigned As[32][17];
    __shared__ unsigned Bs[64][17];
    int b0 = blockIdx.x * 32, o0 = blockIdx.y * 64;
    int tid = threadIdx.x;
    int ry = tid >> 4, cx = tid & 15;         // rows ry*2+i, cols cx*4+j
    int acc[2][4] = {};
    for (int k0 = 0; k0 < NC; k0 += 64) {
        {
            int row = tid >> 3, o8 = (tid & 7) * 8;
            uint2 va = *(const uint2*)(a1k + (size_t)(b0 + row) * NC + k0 + o8);
            As[row][o8 >> 2] = va.x; As[row][(o8 >> 2) + 1] = va.y;
        }
        {
            int row = tid >> 2, o16 = (tid & 3) * 16;
            uint4 vb = make_uint4(0u, 0u, 0u, 0u);
            if (o0 + row < NO)
                vb = *(const uint4*)(fcr + (size_t)(o0 + row) * NC + k0 + o16);
            Bs[row][o16 >> 2] = vb.x; Bs[row][(o16 >> 2) + 1] = vb.y;
            Bs[row][(o16 >> 2) + 2] = vb.z; Bs[row][(o16 >> 2) + 3] = vb.w;
        }
        __syncthreads();
        #pragma unroll
        for (int kd = 0; kd < 16; ++kd) {
            unsigned av[2], bv[4];
            #pragma unroll
            for (int i = 0; i < 2; ++i) av[i] = As[ry * 2 + i][kd];
            #pragma unroll
            for (int j = 0; j < 4; ++j) bv[j] = Bs[cx * 4 + j][kd];
            #pragma unroll
            for (int i = 0; i < 2; ++i)
                #pragma unroll
                for (int j = 0; j < 4; ++j)
                    acc[i][j] = DOT4(av[i], bv[j], acc[i][j]);
        }
        __syncthreads();
    }
    double s_a1 = (double)alpha1[0] / 255.0;
    double s_fc = (double)mx[2] / 127.0;
    double m = s_a1 * s_fc;
    #pragma unroll
    for (int j = 0; j < 4; ++j) {
        int o = o0 + cx * 4 + j;
        if (o < NO) {
            int corr = 128 * sumr[o];
            double bi = (double)bias[o];
            #pragma unroll
            for (int i = 0; i < 2; ++i) {
                int b = b0 + ry * 2 + i;
                out[(size_t)b * NO + o] = (float)((double)(acc[i][j] + corr) * m + bi);
            }
        }
    }
}

extern "C" void kernel_launch(void* const* d_in, const int* in_sizes, int n_in,
                              void* d_out, int out_size, void* d_ws, size_t ws_size,
                              hipStream_t stream) {
    const float* act     = (const float*)d_in[0];
    const float* conv0_w = (const float*)d_in[2];
    const float* bn0g = (const float*)d_in[3];
    const float* bn0b = (const float*)d_in[4];
    const float* bn0m = (const float*)d_in[5];
    const float* bn0v = (const float*)d_in[6];
    const float* alpha0 = (const float*)d_in[7];
    const float* conv1_w = (const float*)d_in[8];
    const float* bn1g = (const float*)d_in[9];
    const float* bn1b = (const float*)d_in[10];
    const float* bn1m = (const float*)d_in[11];
    const float* bn1v = (const float*)d_in[12];
    const float* alpha1 = (const float*)d_in[13];
    const float* fc_w = (const float*)d_in[14];
    const float* fc_b = (const float*)d_in[15];

    char* base = (char*)d_ws;
    unsigned* mxu = (unsigned*)(base + OFF_MX);
    const float* mxf = (const float*)(base + OFF_MX);
    double* w0t  = (double*)(base + OFF_W0T);
    double* poolt= (double*)(base + OFF_POOL);
    char* a0k    = (char*)(base + OFF_A0K);
    char* w1r    = (char*)(base + OFF_W1R);
    int* sumr1   = (int*)(base + OFF_SUMR1);
    char* a1k    = (char*)(base + OFF_A1K);
    char* fcr    = (char*)(base + OFF_FCR);
    int* sumfc   = (int*)(base + OFF_SUMFC);
    float* out   = (float*)d_out;

    k_init<<<1, 64, 0, stream>>>(mxu);
    k_absmax<<<256, 256, 0, stream>>>(conv0_w, 98304, mxu + 0);
    k_absmax<<<256, 256, 0, stream>>>(conv1_w, 2457600, mxu + 1);
    k_absmax<<<256, 256, 0, stream>>>(fc_w, 768000, mxu + 2);

    k_qw0t<<<384, 256, 0, stream>>>(conv0_w, mxf, w0t);
    k_qwrow<<<768, 256, 0, stream>>>(conv1_w, K1, mxf, 1, w1r, sumr1);
    k_qwrow<<<1000, 256, 0, stream>>>(fc_w, NC, mxf, 2, fcr, sumfc);

    k_pool<<<24576, 256, 0, stream>>>(act, poolt);
    k_conv0<<<200, 256, 0, stream>>>(poolt, w0t, bn0g, bn0b, bn0m, bn0v, alpha0, a0k);
    k_conv1<<<dim3(8, 24), 256, 0, stream>>>(a0k, w1r, sumr1, bn1g, bn1b, bn1m, bn1v,
                                             alpha0, alpha1, mxf, a1k);
    k_fc<<<dim3(8, 16), 256, 0, stream>>>(a1k, fcr, sumfc, alpha1, mxf, fc_b, out);
}

// Round 5
// 527.748 us; speedup vs baseline: 3.3028x; 1.0865x over previous
//
#include <hip/hip_runtime.h>

// pipeline: pool(f64 sums -> f32 store) -> conv0 (f64 GEMM, fused bn+actq -> i8)
//           -> conv1 (exact int GEMM, ksplit 5) -> bnq1 -> fc (int, ksplit 2) -> out
#define NB 256
#define NC 768
#define HW 289
#define NP 25
#define OC0 128
#define K1 3200
#define NO 1000
#define M0 6400   // NB*NP

// ws layout in BYTES (all 256-aligned)
#define OFF_MX    0
#define OFF_W0T   256                          // f64 [768][128]
#define OFF_POOL  (OFF_W0T + 786432)           // f32 [6400][768]
#define OFF_A0K   (OFF_POOL + 19660800)        // i8  [256][3200]
#define OFF_W1R   (OFF_A0K + 819200)           // i8  [768][3200]
#define OFF_SUMR1 (OFF_W1R + 2457600)          // i32 768
#define OFF_A1K   (OFF_SUMR1 + 4096)           // i8  [256][768]
#define OFF_FCR   (OFF_A1K + 196608)           // i8  [1000][768]
#define OFF_SUMFC (OFF_FCR + 768000)           // i32 1000
#define OFF_P1    (OFF_SUMFC + 4096)           // i32 [5][256][768]
#define OFF_PFC   (OFF_P1 + 3932160)           // i32 [2][256][1000]

#if __has_builtin(__builtin_amdgcn_sdot4)
__device__ __forceinline__ int DOT4(unsigned a, unsigned b, int c) {
    return __builtin_amdgcn_sdot4((int)a, (int)b, c, false);
}
#else
__device__ __forceinline__ int DOT4(unsigned a, unsigned b, int c) {
    #pragma unroll
    for (int q = 0; q < 4; ++q)
        c += (int)(char)(a >> (8*q)) * (int)(char)(b >> (8*q));
    return c;
}
#endif

__global__ void k_init(unsigned* mx) {
    if (threadIdx.x < 3) mx[threadIdx.x] = 0u;
}

__global__ void k_absmax(const float* __restrict__ w, int n, unsigned* __restrict__ out) {
    float m = 0.f;
    for (int i = blockIdx.x * blockDim.x + threadIdx.x; i < n; i += gridDim.x * blockDim.x)
        m = fmaxf(m, fabsf(w[i]));
    #pragma unroll
    for (int off = 32; off; off >>= 1) m = fmaxf(m, __shfl_down(m, off));
    __shared__ float sm[4];
    if ((threadIdx.x & 63) == 0) sm[threadIdx.x >> 6] = m;
    __syncthreads();
    if (threadIdx.x == 0)
        atomicMax(out, __float_as_uint(fmaxf(fmaxf(sm[0], sm[1]), fmaxf(sm[2], sm[3]))));
}

// conv0 weights [oc=128][ic=768] -> transposed quantized f64 [ic][oc]
__global__ void k_qw0t(const float* __restrict__ w, const float* __restrict__ mx,
                       double* __restrict__ out) {
    int i = blockIdx.x * 256 + threadIdx.x;           // 98304
    double scale = (double)mx[0] / 127.0;
    int ic = i >> 7, oc = i & 127;
    double r = rint((double)w[oc * 768 + ic] / scale);
    r = fmin(fmax(r, -127.0), 127.0);
    out[i] = r * scale;
}

// per-row weight quant to i8 + row-sum
__global__ __launch_bounds__(256) void k_qwrow(const float* __restrict__ w, int rowlen,
                                               const float* __restrict__ mx, int mxi,
                                               char* __restrict__ out, int* __restrict__ sumr) {
    int row = blockIdx.x;
    double scale = (double)mx[mxi] / 127.0;
    const float* wr = w + (size_t)row * rowlen;
    char* orow = out + (size_t)row * rowlen;
    int s = 0;
    for (int t = threadIdx.x; t < rowlen; t += 256) {
        double r = rint((double)wr[t] / scale);
        r = fmin(fmax(r, -127.0), 127.0);
        int ri = (int)r;
        s += ri;
        orow[t] = (char)ri;
    }
    #pragma unroll
    for (int off = 32; off; off >>= 1) s += __shfl_down(s, off);
    __shared__ int sm[4];
    if ((threadIdx.x & 63) == 0) sm[threadIdx.x >> 6] = s;
    __syncthreads();
    if (threadIdx.x == 0) sumr[row] = sm[0] + sm[1] + sm[2] + sm[3];
}

// avg_pool 5x5 s3 -> pool_t[(b*25+p)*768 + ic] f32 (f64 window sums)
__global__ __launch_bounds__(256) void k_pool(const float* __restrict__ x,
                                              float* __restrict__ pool_t) {
    __shared__ float tile[8 * HW];
    int g = blockIdx.x;                       // 24576 = 256 b * 96 icg
    int b = g / 96, icg = g % 96;
    const float* src = x + (size_t)g * (8 * HW);
    for (int i = threadIdx.x; i < 8 * HW; i += 256) tile[i] = src[i];
    __syncthreads();
    int t = threadIdx.x;
    if (t < 200) {
        int p = t >> 3, pl = t & 7;
        int oh = p / 5, ow = p % 5;
        const float* tp = tile + pl * HW + oh * 51 + ow * 3;
        double s = 0.0;
        #pragma unroll
        for (int kh = 0; kh < 5; ++kh)
            #pragma unroll
            for (int kw = 0; kw < 5; ++kw) s += (double)tp[kh * 17 + kw];
        pool_t[((size_t)b * NP + p) * NC + icg * 8 + pl] = (float)(s / 25.0);
    }
}

// conv0: f64 GEMM C[6400x128] = pool_t[6400x768] * w0t[768x128], fused bn0+relu+actq
// grid (400 m-tiles of 16, 2 oc-halves of 64), block 256, per thread 2x2 f64 acc
__global__ __launch_bounds__(256) void k_conv0(const float* __restrict__ A,
                                               const double* __restrict__ w0t,
                                               const float* __restrict__ g,
                                               const float* __restrict__ be,
                                               const float* __restrict__ mn,
                                               const float* __restrict__ vr,
                                               const float* __restrict__ alpha,
                                               char* __restrict__ a0k) {
    __shared__ double Ast[32][18];            // kk-major: Ast[kk][row]
    __shared__ double Bs[32][65];             // kk-major: Bs[kk][col]
    int m0 = blockIdx.x * 16;
    int oc0 = blockIdx.y * 64;
    int tid = threadIdx.x;
    int ty = tid >> 5, tx = tid & 31;         // rows ty*2+i, cols tx+32*j
    double acc[2][2] = {};
    for (int k0 = 0; k0 < NC; k0 += 32) {
        {   // stage A: 16 rows x 32 kk f32 -> f64, kk-major
            int r = tid >> 4, kk2 = (tid & 15) * 2;
            float2 v = *(const float2*)(A + (size_t)(m0 + r) * NC + k0 + kk2);
            Ast[kk2][r] = (double)v.x;
            Ast[kk2 + 1][r] = (double)v.y;
        }
        #pragma unroll
        for (int l = 0; l < 4; ++l) {          // stage B: 32 kk x 64 cols f64
            int e = tid + l * 256;
            int r = e >> 5, c2 = (e & 31) * 2;
            double2 v = *(const double2*)(w0t + (size_t)(k0 + r) * OC0 + oc0 + c2);
            Bs[r][c2] = v.x; Bs[r][c2 + 1] = v.y;
        }
        __syncthreads();
        #pragma unroll
        for (int kk = 0; kk < 32; ++kk) {
            double av0 = Ast[kk][ty * 2], av1 = Ast[kk][ty * 2 + 1];
            double bv0 = Bs[kk][tx], bv1 = Bs[kk][tx + 32];
            acc[0][0] += av0 * bv0; acc[0][1] += av0 * bv1;
            acc[1][0] += av1 * bv0; acc[1][1] += av1 * bv1;
        }
        __syncthreads();
    }
    double a = (double)alpha[0];
    double s = a / 255.0;
    #pragma unroll
    for (int j = 0; j < 2; ++j) {
        int oc = oc0 + tx + 32 * j;
        double inv = (double)g[oc] / sqrt((double)vr[oc] + 1e-3);
        double sh = (double)be[oc] - (double)mn[oc] * inv;
        #pragma unroll
        for (int i = 0; i < 2; ++i) {
            int m = m0 + ty * 2 + i;
            int b = m / 25, p = m % 25;
            double y = acc[i][j] * inv + sh;
            y = fmax(y, 0.0); y = fmin(y, a);
            int k = (int)rint(y / s);
            a0k[(size_t)b * K1 + oc * 25 + p] = (char)(k - 128);
        }
    }
}

// conv1 partials: C[kz][256x768] = a0k[:, kz-chunk] . w1r[:, kz-chunk]^T (i32 exact)
__global__ __launch_bounds__(256) void k_conv1(const char* __restrict__ a0k,
                                               const char* __restrict__ w1r,
                                               int* __restrict__ part) {
    __shared__ unsigned As[32][17];
    __shared__ unsigned Bs[32][17];
    int b0 = blockIdx.x * 32, oc0 = blockIdx.y * 32;
    int kbeg = blockIdx.z * 640;
    int tid = threadIdx.x;
    int ty = tid >> 4, tx = tid & 15;
    int acc[2][2] = {};
    for (int k0 = kbeg; k0 < kbeg + 640; k0 += 64) {
        int row = tid >> 3, o8 = (tid & 7) * 8;
        uint2 va = *(const uint2*)(a0k + (size_t)(b0 + row) * K1 + k0 + o8);
        As[row][o8 >> 2] = va.x; As[row][(o8 >> 2) + 1] = va.y;
        uint2 vb = *(const uint2*)(w1r + (size_t)(oc0 + row) * K1 + k0 + o8);
        Bs[row][o8 >> 2] = vb.x; Bs[row][(o8 >> 2) + 1] = vb.y;
        __syncthreads();
        #pragma unroll
        for (int kd = 0; kd < 16; ++kd) {
            unsigned av[2], bv[2];
            av[0] = As[ty * 2][kd];     av[1] = As[ty * 2 + 1][kd];
            bv[0] = Bs[tx * 2][kd];     bv[1] = Bs[tx * 2 + 1][kd];
            #pragma unroll
            for (int i = 0; i < 2; ++i)
                #pragma unroll
                for (int j = 0; j < 2; ++j)
                    acc[i][j] = DOT4(av[i], bv[j], acc[i][j]);
        }
        __syncthreads();
    }
    int* pp = part + (size_t)blockIdx.z * (NB * NC);
    #pragma unroll
    for (int i = 0; i < 2; ++i)
        #pragma unroll
        for (int j = 0; j < 2; ++j)
            pp[(size_t)(b0 + ty * 2 + i) * NC + oc0 + tx * 2 + j] = acc[i][j];
}

// reduce conv1 partials + bn1 + relu + actq -> a1k
__global__ __launch_bounds__(256) void k_bnq1(const int* __restrict__ part,
                                              const int* __restrict__ sumr,
                                              const float* __restrict__ g,
                                              const float* __restrict__ be,
                                              const float* __restrict__ mn,
                                              const float* __restrict__ vr,
                                              const float* __restrict__ alpha0,
                                              const float* __restrict__ alpha1,
                                              const float* __restrict__ mx,
                                              char* __restrict__ a1k) {
    int t = blockIdx.x * 256 + threadIdx.x;   // 196608
    int oc = t % NC;
    int s = 128 * sumr[oc];
    #pragma unroll
    for (int kz = 0; kz < 5; ++kz) s += part[(size_t)kz * (NB * NC) + t];
    double m = ((double)alpha0[0] / 255.0) * ((double)mx[1] / 127.0);
    double inv = (double)g[oc] / sqrt((double)vr[oc] + 1e-3);
    double sh = (double)be[oc] - (double)mn[oc] * inv;
    double a = (double)alpha1[0];
    double s1 = a / 255.0;
    double y = (double)s * m * inv + sh;
    y = fmax(y, 0.0); y = fmin(y, a);
    int k = (int)rint(y / s1);
    a1k[t] = (char)(k - 128);
}

// fc partials: [kz][256x1000] i32
__global__ __launch_bounds__(256) void k_fc(const char* __restrict__ a1k,
                                            const char* __restrict__ fcr,
                                            int* __restrict__ part) {
    __shared__ unsigned As[32][17];
    __shared__ unsigned Bs[64][17];
    int b0 = blockIdx.x * 32, o0 = blockIdx.y * 64;
    int kbeg = blockIdx.z * 384;
    int tid = threadIdx.x;
    int ry = tid >> 4, cx = tid & 15;
    int acc[2][4] = {};
    for (int k0 = kbeg; k0 < kbeg + 384; k0 += 64) {
        {
            int row = tid >> 3, o8 = (tid & 7) * 8;
            uint2 va = *(const uint2*)(a1k + (size_t)(b0 + row) * NC + k0 + o8);
            As[row][o8 >> 2] = va.x; As[row][(o8 >> 2) + 1] = va.y;
        }
        {
            int row = tid >> 2, o16 = (tid & 3) * 16;
            uint4 vb = make_uint4(0u, 0u, 0u, 0u);
            if (o0 + row < NO)
                vb = *(const uint4*)(fcr + (size_t)(o0 + row) * NC + k0 + o16);
            Bs[row][o16 >> 2] = vb.x; Bs[row][(o16 >> 2) + 1] = vb.y;
            Bs[row][(o16 >> 2) + 2] = vb.z; Bs[row][(o16 >> 2) + 3] = vb.w;
        }
        __syncthreads();
        #pragma unroll
        for (int kd = 0; kd < 16; ++kd) {
            unsigned av[2], bv[4];
            #pragma unroll
            for (int i = 0; i < 2; ++i) av[i] = As[ry * 2 + i][kd];
            #pragma unroll
            for (int j = 0; j < 4; ++j) bv[j] = Bs[cx * 4 + j][kd];
            #pragma unroll
            for (int i = 0; i < 2; ++i)
                #pragma unroll
                for (int j = 0; j < 4; ++j)
                    acc[i][j] = DOT4(av[i], bv[j], acc[i][j]);
        }
        __syncthreads();
    }
    int* pp = part + (size_t)blockIdx.z * (NB * NO);
    #pragma unroll
    for (int j = 0; j < 4; ++j) {
        int o = o0 + cx * 4 + j;
        if (o < NO)
            #pragma unroll
            for (int i = 0; i < 2; ++i)
                pp[(size_t)(b0 + ry * 2 + i) * NO + o] = acc[i][j];
    }
}

// fc reduce + scale + bias -> f32 out
__global__ __launch_bounds__(256) void k_out(const int* __restrict__ part,
                                             const int* __restrict__ sumr,
                                             const float* __restrict__ alpha1,
                                             const float* __restrict__ mx,
                                             const float* __restrict__ bias,
                                             float* __restrict__ out) {
    int t = blockIdx.x * 256 + threadIdx.x;   // 256000
    int o = t % NO;
    int s = 128 * sumr[o] + part[t] + part[(size_t)(NB * NO) + t];
    double m = ((double)alpha1[0] / 255.0) * ((double)mx[2] / 127.0);
    out[t] = (float)((double)s * m + (double)bias[o]);
}

extern "C" void kernel_launch(void* const* d_in, const int* in_sizes, int n_in,
                              void* d_out, int out_size, void* d_ws, size_t ws_size,
                              hipStream_t stream) {
    const float* act     = (const float*)d_in[0];
    const float* conv0_w = (const float*)d_in[2];
    const float* bn0g = (const float*)d_in[3];
    const float* bn0b = (const float*)d_in[4];
    const float* bn0m = (const float*)d_in[5];
    const float* bn0v = (const float*)d_in[6];
    const float* alpha0 = (const float*)d_in[7];
    const float* conv1_w = (const float*)d_in[8];
    const float* bn1g = (const float*)d_in[9];
    const float* bn1b = (const float*)d_in[10];
    const float* bn1m = (const float*)d_in[11];
    const float* bn1v = (const float*)d_in[12];
    const float* alpha1 = (const float*)d_in[13];
    const float* fc_w = (const float*)d_in[14];
    const float* fc_b = (const float*)d_in[15];

    char* base = (char*)d_ws;
    unsigned* mxu = (unsigned*)(base + OFF_MX);
    const float* mxf = (const float*)(base + OFF_MX);
    double* w0t  = (double*)(base + OFF_W0T);
    float* poolt = (float*)(base + OFF_POOL);
    char* a0k    = (char*)(base + OFF_A0K);
    char* w1r    = (char*)(base + OFF_W1R);
    int* sumr1   = (int*)(base + OFF_SUMR1);
    char* a1k    = (char*)(base + OFF_A1K);
    char* fcr    = (char*)(base + OFF_FCR);
    int* sumfc   = (int*)(base + OFF_SUMFC);
    int* part1   = (int*)(base + OFF_P1);
    int* partfc  = (int*)(base + OFF_PFC);
    float* out   = (float*)d_out;

    k_init<<<1, 64, 0, stream>>>(mxu);
    k_absmax<<<256, 256, 0, stream>>>(conv0_w, 98304, mxu + 0);
    k_absmax<<<256, 256, 0, stream>>>(conv1_w, 2457600, mxu + 1);
    k_absmax<<<256, 256, 0, stream>>>(fc_w, 768000, mxu + 2);

    k_qw0t<<<384, 256, 0, stream>>>(conv0_w, mxf, w0t);
    k_qwrow<<<768, 256, 0, stream>>>(conv1_w, K1, mxf, 1, w1r, sumr1);
    k_qwrow<<<1000, 256, 0, stream>>>(fc_w, NC, mxf, 2, fcr, sumfc);

    k_pool<<<24576, 256, 0, stream>>>(act, poolt);
    k_conv0<<<dim3(400, 2), 256, 0, stream>>>(poolt, w0t, bn0g, bn0b, bn0m, bn0v,
                                              alpha0, a0k);
    k_conv1<<<dim3(8, 24, 5), 256, 0, stream>>>(a0k, w1r, part1);
    k_bnq1<<<768, 256, 0, stream>>>(part1, sumr1, bn1g, bn1b, bn1m, bn1v,
                                    alpha0, alpha1, mxf, a1k);
    k_fc<<<dim3(8, 16, 2), 256, 0, stream>>>(a1k, fcr, partfc);
    k_out<<<1000, 256, 0, stream>>>(partfc, sumfc, alpha1, mxf, fc_b, out);
}